// Round 14
// baseline (1464.926 us; speedup 1.0000x reference)
//
#include <hip/hip_runtime.h>

// Problem constants
#define NROW   8192     // B*T
#define DMODEL 512
#define TSEQ   1024
#define LAYERS 11
#define HIDDEN 1536

typedef __bf16 bf16_t;
typedef bf16_t bf16x8 __attribute__((ext_vector_type(8)));
typedef bf16_t bf16x4 __attribute__((ext_vector_type(4)));
typedef bf16_t bf16x2 __attribute__((ext_vector_type(2)));
typedef float  f32x4  __attribute__((ext_vector_type(4)));
typedef unsigned int u32;
typedef u32 u32x4 __attribute__((ext_vector_type(4)));

#define GLD16(gp, lp) __builtin_amdgcn_global_load_lds( \
    (const __attribute__((address_space(1))) void*)(gp), \
    (__attribute__((address_space(3))) void*)(lp), 16, 0, 0)

#if __has_builtin(__builtin_amdgcn_exp2f)
#define EXP2(x) __builtin_amdgcn_exp2f(x)
#else
#define EXP2(x) exp2f(x)
#endif

// ---------------------------------------------------------------------------
__global__ void rope_table_k(float* __restrict__ cosT, float* __restrict__ sinT) {
    int i = blockIdx.x * blockDim.x + threadIdx.x;   // 0..32767
    int t = i >> 5, j = i & 31;
    float freq = powf(10000.f, -(float)j * (1.f / 32.f));
    float ang = (float)t * freq;
    cosT[i] = cosf(ang);
    sinT[i] = sinf(ang);
}

// ---------------------------------------------------------------------------
// h (f32 master) and hb (bf16 copy) both written
__global__ void embed_gather_k(const int* __restrict__ x,
                               const float* __restrict__ embed,
                               float* __restrict__ h,
                               bf16_t* __restrict__ hb) {
    int n = blockIdx.x;
    int d = threadIdx.x;                     // 0..127
    float4 v = ((const float4*)(embed + (size_t)x[n] * DMODEL))[d];
    ((float4*)(h + (size_t)n * DMODEL))[d] = v;
    bf16x4 o;
    o[0] = (bf16_t)v.x; o[1] = (bf16_t)v.y; o[2] = (bf16_t)v.z; o[3] = (bf16_t)v.w;
    *(bf16x4*)(hb + (size_t)n * DMODEL + d * 4) = o;
}

// ---------------------------------------------------------------------------
// writes bigram A-slice into fused-A cols 512..639 (row stride 640)
__global__ void bg_gather_k(const int* __restrict__ x,
                            const float* __restrict__ bge,
                            bf16_t* __restrict__ Afu) {
    int n = blockIdx.x;
    int t = n & (TSEQ - 1);
    int prev = (t == 0) ? 0 : x[n - 1];      // < 1024 < NB=2048
    Afu[(size_t)n * 640 + 512 + threadIdx.x] = (bf16_t)bge[(size_t)prev * 128 + threadIdx.x];
}

// ---------------------------------------------------------------------------
__global__ void cvt_bf16_k(const float* __restrict__ in, bf16_t* __restrict__ out, int n8) {
    int i = blockIdx.x * blockDim.x + threadIdx.x;
    if (i >= n8) return;
    float4 a = ((const float4*)in)[2 * i];
    float4 b = ((const float4*)in)[2 * i + 1];
    bf16x8 o;
    o[0] = (bf16_t)a.x; o[1] = (bf16_t)a.y; o[2] = (bf16_t)a.z; o[3] = (bf16_t)a.w;
    o[4] = (bf16_t)b.x; o[5] = (bf16_t)b.y; o[6] = (bf16_t)b.z; o[7] = (bf16_t)b.w;
    ((bf16x8*)out)[i] = o;
}

// ---------------------------------------------------------------------------
// f32 -> bf16 with per-K norm-weight fold: out[l,n,k] = in[l,n,k]*nw[l,k]
__global__ void cvt_fold_k(const float* __restrict__ in,
                           const float* __restrict__ nw,
                           bf16_t* __restrict__ out, int n8, int layerSz) {
    int i = blockIdx.x * blockDim.x + threadIdx.x;
    if (i >= n8) return;
    int i8 = i * 8;
    int k = i8 & 511;
    int l = i8 / layerSz;
    const float* wv = nw + l * DMODEL + k;
    float4 a = ((const float4*)in)[2 * i];
    float4 b = ((const float4*)in)[2 * i + 1];
    float4 wa = *(const float4*)wv;
    float4 wb = *(const float4*)(wv + 4);
    bf16x8 o;
    o[0] = (bf16_t)(a.x * wa.x); o[1] = (bf16_t)(a.y * wa.y);
    o[2] = (bf16_t)(a.z * wa.z); o[3] = (bf16_t)(a.w * wa.w);
    o[4] = (bf16_t)(b.x * wb.x); o[5] = (bf16_t)(b.y * wb.y);
    o[6] = (bf16_t)(b.z * wb.z); o[7] = (bf16_t)(b.w * wb.w);
    ((bf16x8*)out)[i] = o;
}

// ---------------------------------------------------------------------------
// f32 [rows][cols] -> bf16 into [rows][640] at colOff  (cols = 1<<lshift)
__global__ void cvt_pad_k(const float* __restrict__ in, bf16_t* __restrict__ out,
                          int n8, int lshift, int mask, int colOff) {
    int i = blockIdx.x * blockDim.x + threadIdx.x;
    if (i >= n8) return;
    int i8 = i * 8;
    int row = i8 >> lshift;
    int col = i8 & mask;
    float4 a = ((const float4*)in)[2 * i];
    float4 b = ((const float4*)in)[2 * i + 1];
    bf16x8 o;
    o[0] = (bf16_t)a.x; o[1] = (bf16_t)a.y; o[2] = (bf16_t)a.z; o[3] = (bf16_t)a.w;
    o[4] = (bf16_t)b.x; o[5] = (bf16_t)b.y; o[6] = (bf16_t)b.z; o[7] = (bf16_t)b.w;
    *(bf16x8*)&out[(size_t)row * 640 + colOff + col] = o;
}

// ---------------------------------------------------------------------------
// RMSNorm f32 in -> bf16 out (row stride ostride). One wave per row.
// (final-norm only; per-layer norms are folded into the GEMMs)
__global__ __launch_bounds__(256) void rmsnorm_k(const float* __restrict__ in,
                                                 const float* __restrict__ w,
                                                 bf16_t* __restrict__ out,
                                                 int ostride) {
    int wv = threadIdx.x >> 6, lane = threadIdx.x & 63;
    int row = (blockIdx.x << 2) + wv;
    const float* rp = in + (size_t)row * DMODEL + lane * 8;
    float4 v0 = *(const float4*)(rp);
    float4 v1 = *(const float4*)(rp + 4);
    float ss = v0.x*v0.x + v0.y*v0.y + v0.z*v0.z + v0.w*v0.w
             + v1.x*v1.x + v1.y*v1.y + v1.z*v1.z + v1.w*v1.w;
#pragma unroll
    for (int off = 32; off; off >>= 1) ss += __shfl_xor(ss, off, 64);
    float sc = rsqrtf(ss * (1.f / DMODEL) + 1e-6f);
    const float* wp = w + lane * 8;
    float4 w0 = *(const float4*)(wp);
    float4 w1 = *(const float4*)(wp + 4);
    bf16x8 o;
    o[0] = (bf16_t)(v0.x * sc * w0.x); o[1] = (bf16_t)(v0.y * sc * w0.y);
    o[2] = (bf16_t)(v0.z * sc * w0.z); o[3] = (bf16_t)(v0.w * sc * w0.w);
    o[4] = (bf16_t)(v1.x * sc * w1.x); o[5] = (bf16_t)(v1.y * sc * w1.y);
    o[6] = (bf16_t)(v1.z * sc * w1.z); o[7] = (bf16_t)(v1.w * sc * w1.w);
    *(bf16x8*)(out + (size_t)row * ostride + lane * 8) = o;
}

// ---------------------------------------------------------------------------
// bf16 MFMA GEMM: C[M,N] = A[M,K] @ B[N,K]^T   (round-11 sync structure)
// BM=128: triple-buffered, 2-deep prefetch, 2 barriers/step.
// BM=64:  quad-buffered, 2-deep prefetch, single barrier/step.
// For EPI 2/4 (A = hb, K = 512): row RMS scale computed IN-KERNEL from the
// A-fragments. No scale_k pass.
// EPI: 0 = f32 store
//      1 = f32 += (C prefetched) AND bf16 dual-store to Cb (the hb copy)
//      2 = bf16 store of relu(s[m]*acc)^2   (norm-folded fc1)
//      4 = bf16 store of s[m]*acc with fused RoPE on cols < 1024 (QKV)
template<int BM, int EPI>
__global__ __launch_bounds__(256, 2)
void gemm_mfma(const bf16_t* __restrict__ A,
               const bf16_t* __restrict__ B,
               float* __restrict__ Cf,
               bf16_t* __restrict__ Cb,
               const float* __restrict__ cosT,
               const float* __restrict__ sinT,
               int M, int N, int K, int nbx) {
    constexpr int NT  = 256;
    constexpr int WM  = 2;                         // waves in M
    constexpr int MI  = BM / WM / 16;              // M frags per wave
    constexpr int ACH = (BM * 4) / NT;             // A 16B chunks per thread
    constexpr int BCH = 2;                         // B 16B chunks per thread
    constexpr int NBUF = (BM == 64) ? 4 : 3;
    constexpr bool SCALED = (EPI == 2 || EPI == 4);
    __shared__ __align__(16) bf16_t As[NBUF][BM * 32];
    __shared__ __align__(16) bf16_t Bs[NBUF][128 * 32];
    const int tid = threadIdx.x;
    const int w = tid >> 6, lane = tid & 63;

    // bijective XCD-chunk swizzle: XCD x gets a contiguous work range
    const int nwg = (int)gridDim.x;
    const int bid = blockIdx.x;
    const int swz = (bid & 7) * (nwg >> 3) + (bid >> 3);
    const int bx = swz % nbx, by = swz / nbx;

    const int m0 = by * BM, n0 = bx * 128;
    const int wr = (w >> 1) * (BM / WM), wc = (w & 1) * 64;
    const int fr = lane & 15, fq = lane >> 4;

    f32x4 acc[MI][4] = {};
    float ssq[SCALED ? MI : 1] = {};

    float cold[EPI == 1 ? MI : 1][4][4];
    if constexpr (EPI == 1) {
#pragma unroll
        for (int i = 0; i < MI; ++i)
#pragma unroll
            for (int j = 0; j < 4; ++j)
#pragma unroll
                for (int q = 0; q < 4; ++q)
                    cold[i][j][q] = Cf[(size_t)(m0 + wr + i * 16 + fq * 4 + q) * N
                                       + n0 + wc + j * 16 + fr];
    }

    auto stage = [&](int k0, int buf) {
#pragma unroll
        for (int c = 0; c < ACH; ++c) {
            int idx = c * NT + tid;
            int row = idx >> 2, cs = idx & 3;
            GLD16(A + (size_t)(m0 + row) * K + k0 + cs * 8,
                  &As[buf][(size_t)(c * NT + w * 64) * 8]);
        }
#pragma unroll
        for (int c = 0; c < BCH; ++c) {
            int idx = c * NT + tid;
            int row = idx >> 2, cs = idx & 3;
            GLD16(B + (size_t)(n0 + row) * K + k0 + cs * 8,
                  &Bs[buf][(size_t)(c * NT + w * 64) * 8]);
        }
    };

    const int NK = K >> 5;
    stage(0, 0);
    stage(32, 1);
    for (int k = 0; k < NK; ++k) {
        const int cur = k % NBUF;
        if (k + 2 < NK) {
            stage((k + 2) << 5, (k + 2) % NBUF);
            if constexpr (BM == 128) asm volatile("s_waitcnt vmcnt(8)" ::: "memory");
            else                     asm volatile("s_waitcnt vmcnt(6)" ::: "memory");
        } else if (k + 1 < NK) {
            if constexpr (BM == 128) asm volatile("s_waitcnt vmcnt(4)" ::: "memory");
            else                     asm volatile("s_waitcnt vmcnt(3)" ::: "memory");
        } else {
            asm volatile("s_waitcnt vmcnt(0)" ::: "memory");
        }
        __builtin_amdgcn_s_barrier();
        __builtin_amdgcn_sched_barrier(0);

        bf16x8 a[MI], b[4];
        const bf16_t* ap = &As[cur][(size_t)(wr + fr) * 32 + fq * 8];
        const bf16_t* bp = &Bs[cur][(size_t)(wc + fr) * 32 + fq * 8];
#pragma unroll
        for (int i = 0; i < MI; ++i) a[i] = *(const bf16x8*)(ap + i * 16 * 32);
#pragma unroll
        for (int j = 0; j < 4; ++j)  b[j] = *(const bf16x8*)(bp + j * 16 * 32);
        __builtin_amdgcn_s_setprio(1);
#pragma unroll
        for (int i = 0; i < MI; ++i)
#pragma unroll
            for (int j = 0; j < 4; ++j)
                acc[i][j] = __builtin_amdgcn_mfma_f32_16x16x32_bf16(a[i], b[j], acc[i][j], 0, 0, 0);
        __builtin_amdgcn_s_setprio(0);

        if constexpr (SCALED) {
#pragma unroll
            for (int i = 0; i < MI; ++i)
#pragma unroll
                for (int j = 0; j < 8; ++j) {
                    float f = (float)a[i][j];
                    ssq[i] = fmaf(f, f, ssq[i]);
                }
        }

        if constexpr (NBUF == 3) {
            asm volatile("s_waitcnt lgkmcnt(0)" ::: "memory");
            __builtin_amdgcn_s_barrier();    // all waves done reading buf cur
            __builtin_amdgcn_sched_barrier(0);
        }
    }

    // in-kernel row scales (EPI 2/4)
    float sld[SCALED ? MI : 1][4];
    if constexpr (SCALED) {
#pragma unroll
        for (int i = 0; i < MI; ++i) {
            ssq[i] += __shfl_xor(ssq[i], 16, 64);
            ssq[i] += __shfl_xor(ssq[i], 32, 64);
#pragma unroll
            for (int q = 0; q < 4; ++q) {
                float v = __shfl(ssq[i], fq * 4 + q, 64);
                sld[i][q] = rsqrtf(v * (1.f / DMODEL) + 1e-6f);
            }
        }
    }

    // C/D layout: col = lane&15, row = (lane>>4)*4 + reg
    if (EPI == 4) {
        const bool qk = (n0 + wc) < 1024;   // q,k get RoPE; v plain
#pragma unroll
        for (int i = 0; i < MI; ++i) {
#pragma unroll
            for (int q = 0; q < 4; ++q) {
                int row = m0 + wr + i * 16 + fq * 4 + q;
                size_t rb = (size_t)row * N + n0 + wc;
                float sm = sld[i][q];
                if (qk) {
                    int t = row & (TSEQ - 1);
#pragma unroll
                    for (int j = 0; j < 2; ++j) {
                        int d = j * 16 + fr;
                        float c = cosT[t * 32 + d];
                        float s = sinT[t * 32 + d];
                        float v1 = acc[i][j][q] * sm, v2 = acc[i][j + 2][q] * sm;
                        Cb[rb + j * 16 + fr]       = (bf16_t)(v1 * c - v2 * s);
                        Cb[rb + (j + 2) * 16 + fr] = (bf16_t)(v1 * s + v2 * c);
                    }
                } else {
#pragma unroll
                    for (int j = 0; j < 4; ++j)
                        Cb[rb + j * 16 + fr] = (bf16_t)(acc[i][j][q] * sm);
                }
            }
        }
        return;
    }
#pragma unroll
    for (int i = 0; i < MI; ++i) {
        int row = m0 + wr + i * 16 + fq * 4;
#pragma unroll
        for (int j = 0; j < 4; ++j) {
            int col = n0 + wc + j * 16 + fr;
#pragma unroll
            for (int q = 0; q < 4; ++q) {
                float v = acc[i][j][q];
                size_t off = (size_t)(row + q) * N + col;
                if (EPI == 0)      Cf[off] = v;
                else if (EPI == 1) {
                    float nv = cold[i][j][q] + v;
                    Cf[off] = nv;
                    Cb[off] = (bf16_t)nv;       // hb dual-store
                } else if (EPI == 2) {
                    v = fmaxf(v * sld[i][q], 0.f);
                    Cb[off] = (bf16_t)(v * v);
                }
            }
        }
    }
}

// ---------------------------------------------------------------------------
// MFMA flash attention. Block = 8 waves (512 thr) = one 128-row q-block of
// one (b,h). Grid 512, heavy q-blocks first; bh = bid&63 pins K/V per XCD L2.
// 2-TILE-DEEP pipeline: 3 LDS buffers for K and V^T; every wave issues
// exactly 3 vmem ops per tile (1 K-GLD16 + 2 V-loads); the per-tile closer
// is vmcnt(3) (waits only tile t+1's loads, issued a full tile earlier) —
// never vmcnt(0) in the main loop. V in-flight regs ping-pong statically
// (tile count 2p+2 is even -> unroll-by-2, no runtime-indexed reg arrays).
// V^T LDS layout element-identical to previous rounds (read path unchanged).
__global__ __launch_bounds__(512) void attn_mfma_k(const bf16_t* __restrict__ qkvb,
                                                   bf16_t* __restrict__ outb) {
    __shared__ __align__(16) bf16_t Ks[3][64 * 64];      // [key][slot^] chunk-XOR
    __shared__ __align__(16) bf16_t VsT[3][2 * 64 * 32]; // [s][d][key32^]

    const int tid = threadIdx.x;
    const int w  = tid >> 6;      // 0..7
    const int ln = tid & 63;
    const int lr = ln & 15;       // q-lane
    const int lg = ln >> 4;       // lane group

    const int bid = blockIdx.x;            // 0..511
    const int p  = 7 - (bid >> 6);         // heavy tiers first
    const int bh = bid & 63;
    const int b = bh >> 3, h = bh & 7;
    const int Tn = (p << 1) + 1;           // last tile index (tiles 0..Tn)
    const int tq0  = (p << 7) + w * 16;    // wave's first q-row
    const int qrow = tq0 + lr;
    const int wlastIdx = (tq0 >> 6);       // wave's masked-tile index

    const bf16_t* Qg = qkvb + (size_t)b * TSEQ * 1536 + h * 64;
    const bf16_t* Kg = Qg + 512;
    const bf16_t* Vg = Qg + 1024;

    // V staging: all 8 waves; thread (mk 0..31, md 0..15) loads keys 2mk,2mk+1
    const int mk = tid >> 4;
    const int md = tid & 15;
    const int src0 = lr + 32 * (lg & 1);   // P source lanes: src0, src0+16
    const int fsel = lg >> 1;
    const int gofs = 8 * (lg ^ ((lr >> 2) & 3));   // read granule offset (elems)

    auto KSTAGE = [&](int tI, int buf) {
        int key = w * 8 + (ln >> 3);
        int dc  = (ln & 7) ^ (ln >> 3);
        GLD16(Kg + (size_t)(tI * 64 + key) * 1536 + dc * 8, &Ks[buf][w * 512]);
    };
    auto VLOAD = [&](int tI, bf16x4 (&rv)[2]) {
#pragma unroll
        for (int i = 0; i < 2; ++i)
            rv[i] = *(const bf16x4*)(Vg + (size_t)(tI * 64 + 2 * mk + i) * 1536 + md * 4);
    };
    auto VWRITE = [&](const bf16x4 (&rv)[2], int buf) {
        const int sv = mk >> 4;        // key half
        const int kp = mk & 15;        // key pair within half
        const int m4 = kp >> 1;        // group-of-4 index
        const int lo = kp & 1;         // pair position within group
#pragma unroll
        for (int j = 0; j < 4; ++j) {
            int row = md * 4 + j;
            int gx  = m4 ^ ((md & 3) << 1);
            bf16x2 wv; wv[0] = rv[0][j]; wv[1] = rv[1][j];
            *(bf16x2*)&VsT[buf][sv * 2048 + row * 32 + gx * 4 + lo * 2] = wv;
        }
    };

    // Q regs (B-operand of swapped QK), prescaled by 0.125 * log2(e)
    bf16x8 qreg[2];
    {
        const float QS = 0.1803368801f;
        const bf16_t* qp = Qg + (size_t)qrow * 1536 + lg * 8;
        qreg[0] = *(const bf16x8*)qp;
        qreg[1] = *(const bf16x8*)(qp + 32);
#pragma unroll
        for (int jj = 0; jj < 8; ++jj) {
            qreg[0][jj] = (bf16_t)((float)qreg[0][jj] * QS);
            qreg[1][jj] = (bf16_t)((float)qreg[1][jj] * QS);
        }
    }

    f32x4 accO[4] = {};       // accO[dblk][r] = O[q=qrow][d=dblk*16+lg*4+r]
    float mrun = -1e30f, pl = 0.f, esf = 0.f;

    // one KV tile of flash-attention compute (Ks/VsT buffer bc)
    auto TILE = [&](int t, int bc, bool masked) {
        const int t0 = t * 64;
        // ---- QK^T (swapped): S^T[key][q]  (scores in log2 domain)
        f32x4 sq[4] = {};
        __builtin_amdgcn_s_setprio(1);
#pragma unroll
        for (int kr = 0; kr < 4; ++kr) {
            int key = kr * 16 + lr;
#pragma unroll
            for (int s = 0; s < 2; ++s) {
                int chunk = key * 8 + ((s * 4 + lg) ^ (key & 7));
                bf16x8 kf = *(const bf16x8*)&Ks[bc][chunk * 8];
                sq[kr] = __builtin_amdgcn_mfma_f32_16x16x32_bf16(kf, qreg[s], sq[kr], 0, 0, 0);
            }
        }
        __builtin_amdgcn_s_setprio(0);

        // ---- online softmax; lane's q = qrow, 16 lane-local keys
        float e16[4][4];
        float tm = -1e30f;
        if (masked) {
#pragma unroll
            for (int f = 0; f < 4; ++f)
#pragma unroll
                for (int r = 0; r < 4; ++r) {
                    int key = t0 + f * 16 + lg * 4 + r;
                    float sv = (key <= qrow) ? sq[f][r] : -1e30f;
                    e16[f][r] = sv;
                    tm = fmaxf(tm, sv);
                }
        } else {
#pragma unroll
            for (int f = 0; f < 4; ++f)
#pragma unroll
                for (int r = 0; r < 4; ++r) {
                    e16[f][r] = sq[f][r];
                    tm = fmaxf(tm, sq[f][r]);
                }
        }
        tm = fmaxf(tm, __shfl_xor(tm, 16, 64));
        tm = fmaxf(tm, __shfl_xor(tm, 32, 64));

        // defer-max: only rescale when some lane's max grew by > 8 (log2)
        const bool resc = __any(tm > mrun + 8.f);
        float mnew = resc ? fmaxf(mrun, tm) : mrun;
        float psum = 0.f;
#pragma unroll
        for (int f = 0; f < 4; ++f)
#pragma unroll
            for (int r = 0; r < 4; ++r) {
                float e = EXP2(e16[f][r] - mnew);   // masked: exp2(-huge)=0
                e16[f][r] = e;
                psum += e;
            }
        float pd = 0.f;
        if (masked) {
#pragma unroll
            for (int f = 0; f < 4; ++f)
#pragma unroll
                for (int r = 0; r < 4; ++r) {
                    int key = t0 + f * 16 + lg * 4 + r;
                    pd = (key == qrow) ? e16[f][r] : pd;
                }
        }
        if (resc) {
            float corr = EXP2(mrun - mnew);
            mrun = mnew;
            pl  = pl  * corr + psum;
            esf = esf * corr + pd;
#pragma unroll
            for (int dblk = 0; dblk < 4; ++dblk)
#pragma unroll
                for (int r = 0; r < 4; ++r) accO[dblk][r] *= corr;
        } else {
            pl  += psum;
            esf += pd;
        }

        // ---- pack P rows to bf16 pairs (uniform register indices only)
        u32 plo[4], phi[4];
#pragma unroll
        for (int f = 0; f < 4; ++f) {
            bf16x4 tt;
            tt[0] = (bf16_t)e16[f][0]; tt[1] = (bf16_t)e16[f][1];
            tt[2] = (bf16_t)e16[f][2]; tt[3] = (bf16_t)e16[f][3];
            uint2 pr = __builtin_bit_cast(uint2, tt);
            plo[f] = pr.x; phi[f] = pr.y;
        }

        // ---- PV (swapped): O^T = V^T . P^T
#pragma unroll
        for (int s = 0; s < 2; ++s) {
            u32 a0 = (u32)__shfl((int)plo[s * 2],     src0,      64);
            u32 a1 = (u32)__shfl((int)phi[s * 2],     src0,      64);
            u32 a2 = (u32)__shfl((int)plo[s * 2],     src0 + 16, 64);
            u32 a3 = (u32)__shfl((int)phi[s * 2],     src0 + 16, 64);
            u32 c0 = (u32)__shfl((int)plo[s * 2 + 1], src0,      64);
            u32 c1 = (u32)__shfl((int)phi[s * 2 + 1], src0,      64);
            u32 c2 = (u32)__shfl((int)plo[s * 2 + 1], src0 + 16, 64);
            u32 c3 = (u32)__shfl((int)phi[s * 2 + 1], src0 + 16, 64);
            u32x4 bw;
            bw[0] = fsel ? c0 : a0;
            bw[1] = fsel ? c1 : a1;
            bw[2] = fsel ? c2 : a2;
            bw[3] = fsel ? c3 : a3;
            bf16x8 bfrag = __builtin_bit_cast(bf16x8, bw);
            __builtin_amdgcn_s_setprio(1);
#pragma unroll
            for (int dblk = 0; dblk < 4; ++dblk) {
                bf16x8 av = *(const bf16x8*)&VsT[bc][s * 2048 + (dblk * 16 + lr) * 32 + gofs];
                accO[dblk] = __builtin_amdgcn_mfma_f32_16x16x32_bf16(av, bfrag, accO[dblk], 0, 0, 0);
            }
            __builtin_amdgcn_s_setprio(0);
        }
    };

    bf16x4 rvA[2], rvB[2];

    // prologue: stage tiles 0 and 1; land V(0); tile 1's loads stay in flight
    KSTAGE(0, 0); VLOAD(0, rvB);
    KSTAGE(1, 1); VLOAD(1, rvA);
    asm volatile("s_waitcnt vmcnt(3)" ::: "memory");   // K0,V0 done
    VWRITE(rvB, 0);
    asm volatile("s_waitcnt lgkmcnt(0)" ::: "memory");
    __builtin_amdgcn_s_barrier();
    __builtin_amdgcn_sched_barrier(0);

    int bc = 0, bn = 1, bs2 = 2;
    auto BODY = [&](int t, bf16x4 (&rvLand)[2], bf16x4 (&rvIssue)[2]) {
        const bool issue = (t + 2 <= Tn);
        if (issue) { KSTAGE(t + 2, bs2); VLOAD(t + 2, rvIssue); }
        if (t <= wlastIdx) TILE(t, bc, t == wlastIdx);
        if (t + 1 <= Tn) {
            if (issue) asm volatile("s_waitcnt vmcnt(3)" ::: "memory");
            else       asm volatile("s_waitcnt vmcnt(0)" ::: "memory");
            VWRITE(rvLand, bn);
            asm volatile("s_waitcnt lgkmcnt(0)" ::: "memory");
            __builtin_amdgcn_s_barrier();
            __builtin_amdgcn_sched_barrier(0);
        }
        int tmp = bc; bc = bn; bn = bs2; bs2 = tmp;    // rotate buffers
    };

    for (int t = 0; t <= Tn; t += 2) {     // tile count 2p+2 is even
        BODY(t,     rvA, rvB);
        BODY(t + 1, rvB, rvA);
    }

    // ---- epilogue: reduce l/self-weight over lane groups, subtract, store
    pl  += __shfl_xor(pl, 16, 64);  pl  += __shfl_xor(pl, 32, 64);
    esf += __shfl_xor(esf, 16, 64); esf += __shfl_xor(esf, 32, 64);
    float rin = 1.0f / pl;
    const bf16_t* vqp = Vg + (size_t)qrow * 1536;
    bf16_t* op = outb + (size_t)(b * TSEQ + qrow) * DMODEL + h * 64;
#pragma unroll
    for (int dblk = 0; dblk < 4; ++dblk) {
        bf16x4 vq = *(const bf16x4*)(vqp + dblk * 16 + lg * 4);
        bf16x4 o4;
#pragma unroll
        for (int r = 0; r < 4; ++r)
            o4[r] = (bf16_t)((accO[dblk][r] - esf * (float)vq[r]) * rin);
        *(bf16x4*)(op + dblk * 16 + lg * 4) = o4;
    }
}

// ---------------------------------------------------------------------------
static inline void cvt(const float* in, bf16_t* out, size_t n, hipStream_t s) {
    int n8 = (int)(n / 8);
    cvt_bf16_k<<<(n8 + 255) / 256, 256, 0, s>>>(in, out, n8);
}

extern "C" void kernel_launch(void* const* d_in, const int* in_sizes, int n_in,
                              void* d_out, int out_size, void* d_ws, size_t ws_size,
                              hipStream_t stream) {
    const int*   x     = (const int*)d_in[0];
    const float* embed = (const float*)d_in[1];
    const float* Wqkv  = (const float*)d_in[2];
    const float* Wproj = (const float*)d_in[3];
    const float* n1w   = (const float*)d_in[4];
    const float* n2w   = (const float*)d_in[5];
    const float* Wfc1  = (const float*)d_in[6];
    const float* Wfc2  = (const float*)d_in[7];
    const float* normf = (const float*)d_in[8];
    const float* bge   = (const float*)d_in[9];
    const float* bgp   = (const float*)d_in[10];
    float* out = (float*)d_out;

    // workspace layout (~103 MB)
    float* ws   = (float*)d_ws;
    float* cosT = ws;                            // 32768
    float* sinT = cosT + 32768;                  // 32768
    float* h    = sinT + 32768;                  // 8192*512 f32
    bf16_t* qkvb = (bf16_t*)(h + (size_t)NROW * DMODEL);  // 8192*1536 bf16
    bf16_t* ub   = qkvb;                         // alias: qkvb dead when fc1 runs
    bf16_t* Afu  = qkvb;                         // alias: fused logits A (8192x640)
    bf16_t* hb   = qkvb + (size_t)NROW * 1536;   // bf16 copy of h
    bf16_t* atb  = hb  + (size_t)NROW * DMODEL;
    bf16_t* wqb  = atb + (size_t)NROW * DMODEL;
    bf16_t* wpb  = wqb + (size_t)LAYERS * 3 * DMODEL * DMODEL;
    bf16_t* w1b  = wpb + (size_t)LAYERS * DMODEL * DMODEL;
    bf16_t* w2b  = w1b + (size_t)LAYERS * HIDDEN * DMODEL;
    bf16_t* bfu  = w2b + (size_t)LAYERS * DMODEL * HIDDEN;  // 1024*640 fused B

    rope_table_k<<<128, 256, 0, stream>>>(cosT, sinT);
    embed_gather_k<<<NROW, 128, 0, stream>>>(x, embed, h, hb);

    // weights: fold n1w into Wqkv, n2w into Wfc1 (rmsnorm w is per-K)
    {
        int n8q = (int)((size_t)LAYERS * 3 * DMODEL * DMODEL / 8);
        cvt_fold_k<<<(n8q + 255) / 256, 256, 0, stream>>>(Wqkv, n1w, wqb, n8q, 3 * DMODEL * DMODEL);
        int n81 = (int)((size_t)LAYERS * HIDDEN * DMODEL / 8);
        cvt_fold_k<<<(n81 + 255) / 256, 256, 0, stream>>>(Wfc1, n2w, w1b, n81, HIDDEN * DMODEL);
    }
    cvt(Wproj, wpb, (size_t)LAYERS * DMODEL * DMODEL, stream);
    cvt(Wfc2,  w2b, (size_t)LAYERS * DMODEL * HIDDEN, stream);
    // fused logits B: [1024 rows][640] = [embed | bg_proj]
    cvt_pad_k<<<(65536 + 255) / 256, 256, 0, stream>>>(embed, bfu, 65536, 9, 511, 0);
    cvt_pad_k<<<(16384 + 255) / 256, 256, 0, stream>>>(bgp,   bfu, 16384, 7, 127, 512);

    for (int i = 0; i < LAYERS; ++i) {
        gemm_mfma<128, 4><<<768, 256, 0, stream>>>(
            hb, wqb + (size_t)i * 3 * DMODEL * DMODEL, nullptr, qkvb,
            cosT, sinT, NROW, 3 * DMODEL, DMODEL, 12);
        attn_mfma_k<<<512, 512, 0, stream>>>(qkvb, atb);
        gemm_mfma<64, 1><<<512, 256, 0, stream>>>(
            atb, wpb + (size_t)i * DMODEL * DMODEL, h, hb,
            nullptr, nullptr, NROW, DMODEL, DMODEL, 4);
        gemm_mfma<128, 2><<<768, 256, 0, stream>>>(
            hb, w1b + (size_t)i * HIDDEN * DMODEL, nullptr, ub,
            nullptr, nullptr, NROW, HIDDEN, DMODEL, 12);
        gemm_mfma<64, 1><<<512, 256, 0, stream>>>(
            ub, w2b + (size_t)i * DMODEL * HIDDEN, h, hb,
            nullptr, nullptr, NROW, DMODEL, HIDDEN, 4);
    }

    // fused logits: [rmsnorm(h)*normf | bga] @ [embed | bgp]^T, K = 640
    rmsnorm_k<<<NROW / 4, 256, 0, stream>>>(h, normf, Afu, 640);
    bg_gather_k<<<NROW, 128, 0, stream>>>(x, bge, Afu);
    gemm_mfma<128, 0><<<512, 256, 0, stream>>>(
        Afu, bfu, out, nullptr, nullptr, nullptr, NROW, 1024, 640, 8);
}

// Round 15
// 1443.148 us; speedup vs baseline: 1.0151x; 1.0151x over previous
//
#include <hip/hip_runtime.h>

// Problem constants
#define NROW   8192     // B*T
#define DMODEL 512
#define TSEQ   1024
#define LAYERS 11
#define HIDDEN 1536

typedef __bf16 bf16_t;
typedef bf16_t bf16x8 __attribute__((ext_vector_type(8)));
typedef bf16_t bf16x4 __attribute__((ext_vector_type(4)));
typedef float  f32x4  __attribute__((ext_vector_type(4)));
typedef unsigned int u32;
typedef u32 u32x4 __attribute__((ext_vector_type(4)));

#define GLD16(gp, lp) __builtin_amdgcn_global_load_lds( \
    (const __attribute__((address_space(1))) void*)(gp), \
    (__attribute__((address_space(3))) void*)(lp), 16, 0, 0)

#if __has_builtin(__builtin_amdgcn_exp2f)
#define EXP2(x) __builtin_amdgcn_exp2f(x)
#else
#define EXP2(x) exp2f(x)
#endif

// ---------------------------------------------------------------------------
__global__ void rope_table_k(float* __restrict__ cosT, float* __restrict__ sinT) {
    int i = blockIdx.x * blockDim.x + threadIdx.x;   // 0..32767
    int t = i >> 5, j = i & 31;
    float freq = powf(10000.f, -(float)j * (1.f / 32.f));
    float ang = (float)t * freq;
    cosT[i] = cosf(ang);
    sinT[i] = sinf(ang);
}

// ---------------------------------------------------------------------------
// h (f32 master) and hb (bf16 copy) both written
__global__ void embed_gather_k(const int* __restrict__ x,
                               const float* __restrict__ embed,
                               float* __restrict__ h,
                               bf16_t* __restrict__ hb) {
    int n = blockIdx.x;
    int d = threadIdx.x;                     // 0..127
    float4 v = ((const float4*)(embed + (size_t)x[n] * DMODEL))[d];
    ((float4*)(h + (size_t)n * DMODEL))[d] = v;
    bf16x4 o;
    o[0] = (bf16_t)v.x; o[1] = (bf16_t)v.y; o[2] = (bf16_t)v.z; o[3] = (bf16_t)v.w;
    *(bf16x4*)(hb + (size_t)n * DMODEL + d * 4) = o;
}

// ---------------------------------------------------------------------------
// writes bigram A-slice into fused-A cols 512..639 (row stride 640)
__global__ void bg_gather_k(const int* __restrict__ x,
                            const float* __restrict__ bge,
                            bf16_t* __restrict__ Afu) {
    int n = blockIdx.x;
    int t = n & (TSEQ - 1);
    int prev = (t == 0) ? 0 : x[n - 1];      // < 1024 < NB=2048
    Afu[(size_t)n * 640 + 512 + threadIdx.x] = (bf16_t)bge[(size_t)prev * 128 + threadIdx.x];
}

// ---------------------------------------------------------------------------
__global__ void cvt_bf16_k(const float* __restrict__ in, bf16_t* __restrict__ out, int n8) {
    int i = blockIdx.x * blockDim.x + threadIdx.x;
    if (i >= n8) return;
    float4 a = ((const float4*)in)[2 * i];
    float4 b = ((const float4*)in)[2 * i + 1];
    bf16x8 o;
    o[0] = (bf16_t)a.x; o[1] = (bf16_t)a.y; o[2] = (bf16_t)a.z; o[3] = (bf16_t)a.w;
    o[4] = (bf16_t)b.x; o[5] = (bf16_t)b.y; o[6] = (bf16_t)b.z; o[7] = (bf16_t)b.w;
    ((bf16x8*)out)[i] = o;
}

// ---------------------------------------------------------------------------
// f32 -> bf16 with per-K norm-weight fold: out[l,n,k] = in[l,n,k]*nw[l,k]
__global__ void cvt_fold_k(const float* __restrict__ in,
                           const float* __restrict__ nw,
                           bf16_t* __restrict__ out, int n8, int layerSz) {
    int i = blockIdx.x * blockDim.x + threadIdx.x;
    if (i >= n8) return;
    int i8 = i * 8;
    int k = i8 & 511;
    int l = i8 / layerSz;
    const float* wv = nw + l * DMODEL + k;
    float4 a = ((const float4*)in)[2 * i];
    float4 b = ((const float4*)in)[2 * i + 1];
    float4 wa = *(const float4*)wv;
    float4 wb = *(const float4*)(wv + 4);
    bf16x8 o;
    o[0] = (bf16_t)(a.x * wa.x); o[1] = (bf16_t)(a.y * wa.y);
    o[2] = (bf16_t)(a.z * wa.z); o[3] = (bf16_t)(a.w * wa.w);
    o[4] = (bf16_t)(b.x * wb.x); o[5] = (bf16_t)(b.y * wb.y);
    o[6] = (bf16_t)(b.z * wb.z); o[7] = (bf16_t)(b.w * wb.w);
    ((bf16x8*)out)[i] = o;
}

// ---------------------------------------------------------------------------
// f32 [rows][cols] -> bf16 into [rows][640] at colOff  (cols = 1<<lshift)
__global__ void cvt_pad_k(const float* __restrict__ in, bf16_t* __restrict__ out,
                          int n8, int lshift, int mask, int colOff) {
    int i = blockIdx.x * blockDim.x + threadIdx.x;
    if (i >= n8) return;
    int i8 = i * 8;
    int row = i8 >> lshift;
    int col = i8 & mask;
    float4 a = ((const float4*)in)[2 * i];
    float4 b = ((const float4*)in)[2 * i + 1];
    bf16x8 o;
    o[0] = (bf16_t)a.x; o[1] = (bf16_t)a.y; o[2] = (bf16_t)a.z; o[3] = (bf16_t)a.w;
    o[4] = (bf16_t)b.x; o[5] = (bf16_t)b.y; o[6] = (bf16_t)b.z; o[7] = (bf16_t)b.w;
    *(bf16x8*)&out[(size_t)row * 640 + colOff + col] = o;
}

// ---------------------------------------------------------------------------
// Row RMS scale: s[row] = rsqrt(mean(hb[row]^2)+eps). One wave per row.
__global__ __launch_bounds__(256) void scale_k(const bf16_t* __restrict__ hb,
                                               float* __restrict__ s) {
    int wv = threadIdx.x >> 6, lane = threadIdx.x & 63;
    int row = (blockIdx.x << 2) + wv;
    bf16x8 v = *(const bf16x8*)(hb + (size_t)row * DMODEL + lane * 8);
    float ss = 0.f;
#pragma unroll
    for (int j = 0; j < 8; ++j) { float f = (float)v[j]; ss += f * f; }
#pragma unroll
    for (int off = 32; off; off >>= 1) ss += __shfl_xor(ss, off, 64);
    if (lane == 0) s[row] = rsqrtf(ss * (1.f / DMODEL) + 1e-6f);
}

// ---------------------------------------------------------------------------
// RMSNorm f32 in -> bf16 out (row stride ostride). One wave per row.
// (final-norm only; per-layer norms are folded into the GEMMs)
__global__ __launch_bounds__(256) void rmsnorm_k(const float* __restrict__ in,
                                                 const float* __restrict__ w,
                                                 bf16_t* __restrict__ out,
                                                 int ostride) {
    int wv = threadIdx.x >> 6, lane = threadIdx.x & 63;
    int row = (blockIdx.x << 2) + wv;
    const float* rp = in + (size_t)row * DMODEL + lane * 8;
    float4 v0 = *(const float4*)(rp);
    float4 v1 = *(const float4*)(rp + 4);
    float ss = v0.x*v0.x + v0.y*v0.y + v0.z*v0.z + v0.w*v0.w
             + v1.x*v1.x + v1.y*v1.y + v1.z*v1.z + v1.w*v1.w;
#pragma unroll
    for (int off = 32; off; off >>= 1) ss += __shfl_xor(ss, off, 64);
    float sc = rsqrtf(ss * (1.f / DMODEL) + 1e-6f);
    const float* wp = w + lane * 8;
    float4 w0 = *(const float4*)(wp);
    float4 w1 = *(const float4*)(wp + 4);
    bf16x8 o;
    o[0] = (bf16_t)(v0.x * sc * w0.x); o[1] = (bf16_t)(v0.y * sc * w0.y);
    o[2] = (bf16_t)(v0.z * sc * w0.z); o[3] = (bf16_t)(v0.w * sc * w0.w);
    o[4] = (bf16_t)(v1.x * sc * w1.x); o[5] = (bf16_t)(v1.y * sc * w1.y);
    o[6] = (bf16_t)(v1.z * sc * w1.z); o[7] = (bf16_t)(v1.w * sc * w1.w);
    *(bf16x8*)(out + (size_t)row * ostride + lane * 8) = o;
}

// ---------------------------------------------------------------------------
// bf16 MFMA GEMM: C[M,N] = A[M,K] @ B[N,K]^T
// BM=128: triple-buffered, 2-deep prefetch, 2 barriers/step (3 blocks/CU).
// BM=64:  quad-buffered, 2-deep prefetch, SINGLE barrier/step.
// 1D grid, bijective XCD-chunked swizzle (grid % 8 == 0 always here).
// EPI: 0 = f32 store
//      1 = f32 += (C prefetched) AND bf16 dual-store to Cb (the hb copy)
//      2 = bf16 store of relu(s[m]*acc)^2   (norm-folded fc1)
//      4 = bf16 store of s[m]*acc with fused RoPE on cols < 1024 (QKV)
template<int BM, int EPI>
__global__ __launch_bounds__(256, 2)
void gemm_mfma(const bf16_t* __restrict__ A,
               const bf16_t* __restrict__ B,
               float* __restrict__ Cf,
               bf16_t* __restrict__ Cb,
               const float* __restrict__ cosT,
               const float* __restrict__ sinT,
               const float* __restrict__ Sc,
               int M, int N, int K, int nbx) {
    constexpr int NT  = 256;
    constexpr int WM  = 2;                         // waves in M
    constexpr int MI  = BM / WM / 16;              // M frags per wave
    constexpr int ACH = (BM * 4) / NT;             // A 16B chunks per thread
    constexpr int BCH = 2;                         // B 16B chunks per thread
    constexpr int NBUF = (BM == 64) ? 4 : 3;
    constexpr bool SCALED = (EPI == 2 || EPI == 4);
    __shared__ __align__(16) bf16_t As[NBUF][BM * 32];
    __shared__ __align__(16) bf16_t Bs[NBUF][128 * 32];
    const int tid = threadIdx.x;
    const int w = tid >> 6, lane = tid & 63;

    // bijective XCD-chunk swizzle: XCD x gets a contiguous work range
    const int nwg = (int)gridDim.x;
    const int bid = blockIdx.x;
    const int swz = (bid & 7) * (nwg >> 3) + (bid >> 3);
    const int bx = swz % nbx, by = swz / nbx;

    const int m0 = by * BM, n0 = bx * 128;
    const int wr = (w >> 1) * (BM / WM), wc = (w & 1) * 64;
    const int fr = lane & 15, fq = lane >> 4;

    f32x4 acc[MI][4] = {};

    // Oldest vmem ops: per-row scale (EPI 2/4) or C prefetch (EPI 1).
    float sld[SCALED ? MI : 1][4];
    if constexpr (SCALED) {
#pragma unroll
        for (int i = 0; i < MI; ++i)
#pragma unroll
            for (int q = 0; q < 4; ++q)
                sld[i][q] = Sc[m0 + wr + i * 16 + fq * 4 + q];
    }
    float cold[EPI == 1 ? MI : 1][4][4];
    if constexpr (EPI == 1) {
#pragma unroll
        for (int i = 0; i < MI; ++i)
#pragma unroll
            for (int j = 0; j < 4; ++j)
#pragma unroll
                for (int q = 0; q < 4; ++q)
                    cold[i][j][q] = Cf[(size_t)(m0 + wr + i * 16 + fq * 4 + q) * N
                                       + n0 + wc + j * 16 + fr];
    }

    auto stage = [&](int k0, int buf) {
#pragma unroll
        for (int c = 0; c < ACH; ++c) {
            int idx = c * NT + tid;
            int row = idx >> 2, cs = idx & 3;
            GLD16(A + (size_t)(m0 + row) * K + k0 + cs * 8,
                  &As[buf][(size_t)(c * NT + w * 64) * 8]);
        }
#pragma unroll
        for (int c = 0; c < BCH; ++c) {
            int idx = c * NT + tid;
            int row = idx >> 2, cs = idx & 3;
            GLD16(B + (size_t)(n0 + row) * K + k0 + cs * 8,
                  &Bs[buf][(size_t)(c * NT + w * 64) * 8]);
        }
    };

    const int NK = K >> 5;
    stage(0, 0);
    stage(32, 1);
    for (int k = 0; k < NK; ++k) {
        const int cur = k % NBUF;
        if (k + 2 < NK) {
            stage((k + 2) << 5, (k + 2) % NBUF);
            if constexpr (BM == 128) asm volatile("s_waitcnt vmcnt(8)" ::: "memory");
            else                     asm volatile("s_waitcnt vmcnt(6)" ::: "memory");
        } else if (k + 1 < NK) {
            if constexpr (BM == 128) asm volatile("s_waitcnt vmcnt(4)" ::: "memory");
            else                     asm volatile("s_waitcnt vmcnt(3)" ::: "memory");
        } else {
            asm volatile("s_waitcnt vmcnt(0)" ::: "memory");
        }
        __builtin_amdgcn_s_barrier();
        __builtin_amdgcn_sched_barrier(0);

        bf16x8 a[MI], b[4];
        const bf16_t* ap = &As[cur][(size_t)(wr + fr) * 32 + fq * 8];
        const bf16_t* bp = &Bs[cur][(size_t)(wc + fr) * 32 + fq * 8];
#pragma unroll
        for (int i = 0; i < MI; ++i) a[i] = *(const bf16x8*)(ap + i * 16 * 32);
#pragma unroll
        for (int j = 0; j < 4; ++j)  b[j] = *(const bf16x8*)(bp + j * 16 * 32);
        __builtin_amdgcn_s_setprio(1);
#pragma unroll
        for (int i = 0; i < MI; ++i)
#pragma unroll
            for (int j = 0; j < 4; ++j)
                acc[i][j] = __builtin_amdgcn_mfma_f32_16x16x32_bf16(a[i], b[j], acc[i][j], 0, 0, 0);
        __builtin_amdgcn_s_setprio(0);

        if constexpr (NBUF == 3) {
            asm volatile("s_waitcnt lgkmcnt(0)" ::: "memory");
            __builtin_amdgcn_s_barrier();    // all waves done reading buf cur
            __builtin_amdgcn_sched_barrier(0);
        }
    }

    // C/D layout: col = lane&15, row = (lane>>4)*4 + reg
    if (EPI == 4) {
        // wave's 64 cols = exactly one 64-wide head (n0, wc are 64-aligned)
        const bool qk = (n0 + wc) < 1024;   // q,k get RoPE; v plain
#pragma unroll
        for (int i = 0; i < MI; ++i) {
#pragma unroll
            for (int q = 0; q < 4; ++q) {
                int row = m0 + wr + i * 16 + fq * 4 + q;
                size_t rb = (size_t)row * N + n0 + wc;
                float sm = sld[i][q];
                if (qk) {
                    int t = row & (TSEQ - 1);
#pragma unroll
                    for (int j = 0; j < 2; ++j) {
                        int d = j * 16 + fr;
                        float c = cosT[t * 32 + d];
                        float s = sinT[t * 32 + d];
                        float v1 = acc[i][j][q] * sm, v2 = acc[i][j + 2][q] * sm;
                        Cb[rb + j * 16 + fr]       = (bf16_t)(v1 * c - v2 * s);
                        Cb[rb + (j + 2) * 16 + fr] = (bf16_t)(v1 * s + v2 * c);
                    }
                } else {
#pragma unroll
                    for (int j = 0; j < 4; ++j)
                        Cb[rb + j * 16 + fr] = (bf16_t)(acc[i][j][q] * sm);
                }
            }
        }
        return;
    }
#pragma unroll
    for (int i = 0; i < MI; ++i) {
        int row = m0 + wr + i * 16 + fq * 4;
#pragma unroll
        for (int j = 0; j < 4; ++j) {
            int col = n0 + wc + j * 16 + fr;
#pragma unroll
            for (int q = 0; q < 4; ++q) {
                float v = acc[i][j][q];
                size_t off = (size_t)(row + q) * N + col;
                if (EPI == 0)      Cf[off] = v;
                else if (EPI == 1) {
                    float nv = cold[i][j][q] + v;
                    Cf[off] = nv;
                    Cb[off] = (bf16_t)nv;       // hb dual-store
                } else if (EPI == 2) {
                    v = fmaxf(v * sld[i][q], 0.f);
                    Cb[off] = (bf16_t)(v * v);
                }
            }
        }
    }
}

// ---------------------------------------------------------------------------
// MFMA flash attention. Block = 8 waves (512 thr) = one 128-row q-block of
// one (b,h); each wave owns 16 q-rows. Grid 512, heavy q-blocks first;
// bh = bid&63 keeps each bh's K/V on one XCD's L2.
// Waves whose rows precede a tile skip its compute (barriers stay uniform).
// Softmax exp2-domain; interior tiles unmasked; defer-max.
__global__ __launch_bounds__(512) void attn_mfma_k(const bf16_t* __restrict__ qkvb,
                                                   bf16_t* __restrict__ outb) {
    __shared__ __align__(16) bf16_t Ks[2][64 * 64];      // [key][slot^] chunk-XOR
    __shared__ __align__(16) bf16_t VsT[2][2 * 64 * 32]; // [s][d][key32^]

    const int tid = threadIdx.x;
    const int w  = tid >> 6;      // 0..7
    const int ln = tid & 63;
    const int lr = ln & 15;       // q-lane
    const int lg = ln >> 4;       // lane group

    const int bid = blockIdx.x;            // 0..511
    const int p  = 7 - (bid >> 6);         // heavy tiers first
    const int bh = bid & 63;
    const int b = bh >> 3, h = bh & 7;
    const int lastT = (p << 7) + 64;       // block's last KV-tile base
    const int tq0  = (p << 7) + w * 16;    // wave's first q-row
    const int qrow = tq0 + lr;
    const int wlast = tq0 & ~63;           // wave's masked-tile base

    const bf16_t* Qg = qkvb + (size_t)b * TSEQ * 1536 + h * 64;
    const bf16_t* Kg = Qg + 512;
    const bf16_t* Vg = Qg + 1024;

    // V staging micro-tile (waves 0-3 only): keys mk*4..+3, d md*4..+3
    const int mk = tid >> 4;      // 0..15 for tid<256
    const int md = tid & 15;      // 0..15
    const int src0 = lr + 32 * (lg & 1);   // P source lanes: src0, src0+16
    const int fsel = lg >> 1;
    const int gofs = 8 * (lg ^ ((lr >> 2) & 3));   // read granule offset (elems)

    auto KSTAGE = [&](int t0, int buf) {
        int key = w * 8 + (ln >> 3);
        int dc  = (ln & 7) ^ (ln >> 3);
        GLD16(Kg + (size_t)(t0 + key) * 1536 + dc * 8, &Ks[buf][w * 512]);
    };
    auto VLOAD = [&](int t0, bf16x4* rv) {
#pragma unroll
        for (int i = 0; i < 4; ++i)
            rv[i] = *(const bf16x4*)(Vg + (size_t)(t0 + mk * 4 + i) * 1536 + md * 4);
    };
    auto VWRITE = [&](const bf16x4* rv, int buf) {
        const int s = mk >> 3;
#pragma unroll
        for (int jj = 0; jj < 4; ++jj) {
            int row = md * 4 + jj;
            bf16x4 wv;
            wv[0] = rv[0][jj]; wv[1] = rv[1][jj]; wv[2] = rv[2][jj]; wv[3] = rv[3][jj];
            int gx = (mk & 7) ^ ((md & 3) << 1);
            *(bf16x4*)&VsT[buf][s * 2048 + row * 32 + gx * 4] = wv;
        }
    };

    // Q regs (B-operand of swapped QK), prescaled by 0.125 * log2(e)
    bf16x8 qreg[2];
    {
        const float QS = 0.1803368801f;
        const bf16_t* qp = Qg + (size_t)qrow * 1536 + lg * 8;
        qreg[0] = *(const bf16x8*)qp;
        qreg[1] = *(const bf16x8*)(qp + 32);
#pragma unroll
        for (int jj = 0; jj < 8; ++jj) {
            qreg[0][jj] = (bf16_t)((float)qreg[0][jj] * QS);
            qreg[1][jj] = (bf16_t)((float)qreg[1][jj] * QS);
        }
    }

    f32x4 accO[4] = {};       // accO[dblk][r] = O[q=qrow][d=dblk*16+lg*4+r]
    float mrun = -1e30f, pl = 0.f, esf = 0.f;

    // prologue: stage tile 0 into buf 0
    {
        bf16x4 rv[4];
        KSTAGE(0, 0);
        if (w < 4) VLOAD(0, rv);
        asm volatile("s_waitcnt vmcnt(0)" ::: "memory");
        if (w < 4) VWRITE(rv, 0);
        asm volatile("s_waitcnt lgkmcnt(0)" ::: "memory");
        __builtin_amdgcn_s_barrier();
        __builtin_amdgcn_sched_barrier(0);
    }

    for (int t0 = 0; t0 <= lastT; t0 += 64) {
        const int cur = (t0 >> 6) & 1;
        const bool more = t0 < lastT;
        bf16x4 rv[4];
        if (more) {                     // issue next tile's loads early
            KSTAGE(t0 + 64, cur ^ 1);
            if (w < 4) VLOAD(t0 + 64, rv);
        }

        if (t0 <= wlast) {              // wave has live q-rows for this tile
            const bool masked = t0 == wlast;

            // ---- QK^T (swapped): S^T[key][q]  (scores in log2 domain)
            f32x4 sq[4] = {};
            __builtin_amdgcn_s_setprio(1);
#pragma unroll
            for (int kr = 0; kr < 4; ++kr) {
                int key = kr * 16 + lr;
#pragma unroll
                for (int s = 0; s < 2; ++s) {
                    int chunk = key * 8 + ((s * 4 + lg) ^ (key & 7));
                    bf16x8 kf = *(const bf16x8*)&Ks[cur][chunk * 8];
                    sq[kr] = __builtin_amdgcn_mfma_f32_16x16x32_bf16(kf, qreg[s], sq[kr], 0, 0, 0);
                }
            }
            __builtin_amdgcn_s_setprio(0);

            // ---- online softmax; lane's q = qrow, 16 lane-local keys
            float e16[4][4];
            float tm = -1e30f;
            if (masked) {
#pragma unroll
                for (int f = 0; f < 4; ++f)
#pragma unroll
                    for (int r = 0; r < 4; ++r) {
                        int key = t0 + f * 16 + lg * 4 + r;
                        float sv = (key <= qrow) ? sq[f][r] : -1e30f;
                        e16[f][r] = sv;
                        tm = fmaxf(tm, sv);
                    }
            } else {
#pragma unroll
                for (int f = 0; f < 4; ++f)
#pragma unroll
                    for (int r = 0; r < 4; ++r) {
                        e16[f][r] = sq[f][r];
                        tm = fmaxf(tm, sq[f][r]);
                    }
            }
            tm = fmaxf(tm, __shfl_xor(tm, 16, 64));
            tm = fmaxf(tm, __shfl_xor(tm, 32, 64));

            // defer-max: only rescale when some lane's max grew by > 8 (log2)
            const bool resc = __any(tm > mrun + 8.f);
            float mnew = resc ? fmaxf(mrun, tm) : mrun;
            float psum = 0.f;
#pragma unroll
            for (int f = 0; f < 4; ++f)
#pragma unroll
                for (int r = 0; r < 4; ++r) {
                    float e = EXP2(e16[f][r] - mnew);   // masked: exp2(-huge)=0
                    e16[f][r] = e;
                    psum += e;
                }
            float pd = 0.f;
            if (masked) {
#pragma unroll
                for (int f = 0; f < 4; ++f)
#pragma unroll
                    for (int r = 0; r < 4; ++r) {
                        int key = t0 + f * 16 + lg * 4 + r;
                        pd = (key == qrow) ? e16[f][r] : pd;
                    }
            }
            if (resc) {
                float corr = EXP2(mrun - mnew);
                mrun = mnew;
                pl  = pl  * corr + psum;
                esf = esf * corr + pd;
#pragma unroll
                for (int dblk = 0; dblk < 4; ++dblk)
#pragma unroll
                    for (int r = 0; r < 4; ++r) accO[dblk][r] *= corr;
            } else {
                pl  += psum;
                esf += pd;
            }

            // ---- pack P rows to bf16 pairs (uniform register indices only)
            u32 plo[4], phi[4];
#pragma unroll
            for (int f = 0; f < 4; ++f) {
                bf16x4 t;
                t[0] = (bf16_t)e16[f][0]; t[1] = (bf16_t)e16[f][1];
                t[2] = (bf16_t)e16[f][2]; t[3] = (bf16_t)e16[f][3];
                uint2 pr = __builtin_bit_cast(uint2, t);
                plo[f] = pr.x; phi[f] = pr.y;
            }

            // ---- PV (swapped): O^T = V^T . P^T
#pragma unroll
            for (int s = 0; s < 2; ++s) {
                u32 a0 = (u32)__shfl((int)plo[s * 2],     src0,      64);
                u32 a1 = (u32)__shfl((int)phi[s * 2],     src0,      64);
                u32 a2 = (u32)__shfl((int)plo[s * 2],     src0 + 16, 64);
                u32 a3 = (u32)__shfl((int)phi[s * 2],     src0 + 16, 64);
                u32 c0 = (u32)__shfl((int)plo[s * 2 + 1], src0,      64);
                u32 c1 = (u32)__shfl((int)phi[s * 2 + 1], src0,      64);
                u32 c2 = (u32)__shfl((int)plo[s * 2 + 1], src0 + 16, 64);
                u32 c3 = (u32)__shfl((int)phi[s * 2 + 1], src0 + 16, 64);
                u32x4 bw;
                bw[0] = fsel ? c0 : a0;
                bw[1] = fsel ? c1 : a1;
                bw[2] = fsel ? c2 : a2;
                bw[3] = fsel ? c3 : a3;
                bf16x8 bfrag = __builtin_bit_cast(bf16x8, bw);
                __builtin_amdgcn_s_setprio(1);
#pragma unroll
                for (int dblk = 0; dblk < 4; ++dblk) {
                    bf16x8 av = *(const bf16x8*)&VsT[cur][s * 2048 + (dblk * 16 + lr) * 32 + gofs];
                    accO[dblk] = __builtin_amdgcn_mfma_f32_16x16x32_bf16(av, bfrag, accO[dblk], 0, 0, 0);
                }
                __builtin_amdgcn_s_setprio(0);
            }
        }

        // ---- land next tile's V; close the tile (block-uniform sync)
        if (more) {
            asm volatile("s_waitcnt vmcnt(0)" ::: "memory");
            if (w < 4) VWRITE(rv, cur ^ 1);
            asm volatile("s_waitcnt lgkmcnt(0)" ::: "memory");
            __builtin_amdgcn_s_barrier();
            __builtin_amdgcn_sched_barrier(0);
        }
    }

    // ---- epilogue: reduce l/self-weight over lane groups, subtract, store
    pl  += __shfl_xor(pl, 16, 64);  pl  += __shfl_xor(pl, 32, 64);
    esf += __shfl_xor(esf, 16, 64); esf += __shfl_xor(esf, 32, 64);
    float rin = 1.0f / pl;
    const bf16_t* vqp = Vg + (size_t)qrow * 1536;
    bf16_t* op = outb + (size_t)(b * TSEQ + qrow) * DMODEL + h * 64;
#pragma unroll
    for (int dblk = 0; dblk < 4; ++dblk) {
        bf16x4 vq = *(const bf16x4*)(vqp + dblk * 16 + lg * 4);
        bf16x4 o4;
#pragma unroll
        for (int r = 0; r < 4; ++r)
            o4[r] = (bf16_t)((accO[dblk][r] - esf * (float)vq[r]) * rin);
        *(bf16x4*)(op + dblk * 16 + lg * 4) = o4;
    }
}

// ---------------------------------------------------------------------------
static inline void cvt(const float* in, bf16_t* out, size_t n, hipStream_t s) {
    int n8 = (int)(n / 8);
    cvt_bf16_k<<<(n8 + 255) / 256, 256, 0, s>>>(in, out, n8);
}

extern "C" void kernel_launch(void* const* d_in, const int* in_sizes, int n_in,
                              void* d_out, int out_size, void* d_ws, size_t ws_size,
                              hipStream_t stream) {
    const int*   x     = (const int*)d_in[0];
    const float* embed = (const float*)d_in[1];
    const float* Wqkv  = (const float*)d_in[2];
    const float* Wproj = (const float*)d_in[3];
    const float* n1w   = (const float*)d_in[4];
    const float* n2w   = (const float*)d_in[5];
    const float* Wfc1  = (const float*)d_in[6];
    const float* Wfc2  = (const float*)d_in[7];
    const float* normf = (const float*)d_in[8];
    const float* bge   = (const float*)d_in[9];
    const float* bgp   = (const float*)d_in[10];
    float* out = (float*)d_out;

    // workspace layout (~103 MB)
    float* ws   = (float*)d_ws;
    float* cosT = ws;                            // 32768
    float* sinT = cosT + 32768;                  // 32768
    float* h    = sinT + 32768;                  // 8192*512 f32
    bf16_t* qkvb = (bf16_t*)(h + (size_t)NROW * DMODEL);  // 8192*1536 bf16
    bf16_t* ub   = qkvb;                         // alias: qkvb dead when fc1 runs
    bf16_t* Afu  = qkvb;                         // alias: fused logits A (8192x640)
    bf16_t* hb   = qkvb + (size_t)NROW * 1536;   // bf16 copy of h
    bf16_t* atb  = hb  + (size_t)NROW * DMODEL;
    bf16_t* wqb  = atb + (size_t)NROW * DMODEL;
    bf16_t* wpb  = wqb + (size_t)LAYERS * 3 * DMODEL * DMODEL;
    bf16_t* w1b  = wpb + (size_t)LAYERS * DMODEL * DMODEL;
    bf16_t* w2b  = w1b + (size_t)LAYERS * HIDDEN * DMODEL;
    bf16_t* bfu  = w2b + (size_t)LAYERS * DMODEL * HIDDEN;  // 1024*640 fused B
    float*  sbuf = (float*)(bfu + (size_t)1024 * 640);      // 8192 row scales

    rope_table_k<<<128, 256, 0, stream>>>(cosT, sinT);
    embed_gather_k<<<NROW, 128, 0, stream>>>(x, embed, h, hb);

    // weights: fold n1w into Wqkv, n2w into Wfc1 (rmsnorm w is per-K)
    {
        int n8q = (int)((size_t)LAYERS * 3 * DMODEL * DMODEL / 8);
        cvt_fold_k<<<(n8q + 255) / 256, 256, 0, stream>>>(Wqkv, n1w, wqb, n8q, 3 * DMODEL * DMODEL);
        int n81 = (int)((size_t)LAYERS * HIDDEN * DMODEL / 8);
        cvt_fold_k<<<(n81 + 255) / 256, 256, 0, stream>>>(Wfc1, n2w, w1b, n81, HIDDEN * DMODEL);
    }
    cvt(Wproj, wpb, (size_t)LAYERS * DMODEL * DMODEL, stream);
    cvt(Wfc2,  w2b, (size_t)LAYERS * DMODEL * HIDDEN, stream);
    // fused logits B: [1024 rows][640] = [embed | bg_proj]
    cvt_pad_k<<<(65536 + 255) / 256, 256, 0, stream>>>(embed, bfu, 65536, 9, 511, 0);
    cvt_pad_k<<<(16384 + 255) / 256, 256, 0, stream>>>(bgp,   bfu, 16384, 7, 127, 512);

    for (int i = 0; i < LAYERS; ++i) {
        scale_k<<<NROW / 4, 256, 0, stream>>>(hb, sbuf);
        gemm_mfma<128, 4><<<768, 256, 0, stream>>>(
            hb, wqb + (size_t)i * 3 * DMODEL * DMODEL, nullptr, qkvb,
            cosT, sinT, sbuf, NROW, 3 * DMODEL, DMODEL, 12);
        attn_mfma_k<<<512, 512, 0, stream>>>(qkvb, atb);
        gemm_mfma<64, 1><<<512, 256, 0, stream>>>(
            atb, wpb + (size_t)i * DMODEL * DMODEL, h, hb,
            nullptr, nullptr, nullptr, NROW, DMODEL, DMODEL, 4);
        scale_k<<<NROW / 4, 256, 0, stream>>>(hb, sbuf);
        gemm_mfma<128, 2><<<768, 256, 0, stream>>>(
            hb, w1b + (size_t)i * HIDDEN * DMODEL, nullptr, ub,
            nullptr, nullptr, sbuf, NROW, HIDDEN, DMODEL, 12);
        gemm_mfma<64, 1><<<512, 256, 0, stream>>>(
            ub, w2b + (size_t)i * DMODEL * HIDDEN, h, hb,
            nullptr, nullptr, nullptr, NROW, DMODEL, HIDDEN, 4);
    }

    // fused logits: [rmsnorm(h)*normf | bga] @ [embed | bgp]^T, K = 640
    rmsnorm_k<<<NROW / 4, 256, 0, stream>>>(h, normf, Afu, 640);
    bg_gather_k<<<NROW, 128, 0, stream>>>(x, bge, Afu);
    gemm_mfma<128, 0><<<512, 256, 0, stream>>>(
        Afu, bfu, out, nullptr, nullptr, nullptr, nullptr, NROW, 1024, 640, 8);
}